// Round 1
// baseline (182.135 us; speedup 1.0000x reference)
//
#include <hip/hip_runtime.h>
#include <cstdint>
#include <cstddef>

#define CIN   256
#define COUT  128

typedef float  f32x4  __attribute__((ext_vector_type(4)));
typedef __bf16 bf16x8 __attribute__((ext_vector_type(8)));

// ---------------- workspace layout (bytes) ----------------
#define XPAD_BYTES (16ull*66*66*256*2)          // 35,684,352  bf16 padded x
#define WT_OFF     XPAD_BYTES
#define WT_BYTES   (16ull*128*256*2)            // 1,048,576   bf16 w, [tap][co][ci]
#define SPAD_OFF   (WT_OFF + WT_BYTES)
#define SPAD_BYTES (16ull*66*66*4)              // 278,784     fp32 per-pixel sum(x^2)
#define KSQ_OFF    (SPAD_OFF + SPAD_BYTES)
#define WS_NEEDED  (KSQ_OFF + 512)

__device__ __forceinline__ unsigned short f2bf(float f) {
  unsigned int u = __float_as_uint(f);
  u += 0x7fffu + ((u >> 16) & 1u);              // RNE
  return (unsigned short)(u >> 16);
}

__device__ __forceinline__ void async16(const void* lds, const void* g) {
  __builtin_amdgcn_global_load_lds(
      (const __attribute__((address_space(1))) unsigned int*)g,
      (__attribute__((address_space(3))) unsigned int*)lds, 16, 0, 0);
}

// ---------------- prep: pad+convert x, channel sum of x^2 ----------------
__global__ __launch_bounds__(256) void prep_x(
    const float* __restrict__ x, unsigned short* __restrict__ xpad,
    float* __restrict__ spad)
{
  int wave = threadIdx.x >> 6, lane = threadIdx.x & 63;
  int p = blockIdx.x * 4 + wave;                 // 0..69695 over [16][66][66]
  int b = p / 4356;
  int rem = p - b * 4356;
  int iyp = rem / 66, ixp = rem - iyp * 66;
  bool interior = (iyp >= 1 && iyp <= 64 && ixp >= 1 && ixp <= 64);
  f32x4 v = {0.f, 0.f, 0.f, 0.f};
  if (interior) {
    const float* src = x + (((size_t)b*64 + (iyp-1))*64 + (ixp-1))*CIN + lane*4;
    v = *(const f32x4*)src;
  }
  ushort4 h;
  h.x = f2bf(v.x); h.y = f2bf(v.y); h.z = f2bf(v.z); h.w = f2bf(v.w);
  *(ushort4*)(xpad + (size_t)p*CIN + lane*4) = h;
  float s = v.x*v.x + v.y*v.y + v.z*v.z + v.w*v.w;
  #pragma unroll
  for (int off = 32; off > 0; off >>= 1) s += __shfl_down(s, off);
  if (lane == 0) spad[p] = s;
}

// ---------------- prep: transpose+convert w, k_sq ----------------
__global__ __launch_bounds__(256) void prep_w(
    const float* __restrict__ w, unsigned short* __restrict__ wt,
    float* __restrict__ ksq)
{
  __shared__ __align__(16) unsigned short lw[32*128];
  __shared__ f32x4 red[256];
  int t = threadIdx.x;
  int tap = blockIdx.x >> 3;
  int ci0 = (blockIdx.x & 7) * 32;
  f32x4 sq = {0.f, 0.f, 0.f, 0.f};
  int co4 = (t & 31) * 4;
  #pragma unroll
  for (int i = 0; i < 4; ++i) {
    int ci = (t >> 5) + i*8;
    const float* src = w + ((size_t)(tap*256 + ci0 + ci))*COUT + co4;
    f32x4 v = *(const f32x4*)src;
    sq.x += v.x*v.x; sq.y += v.y*v.y; sq.z += v.z*v.z; sq.w += v.w*v.w;
    ushort4 h; h.x = f2bf(v.x); h.y = f2bf(v.y); h.z = f2bf(v.z); h.w = f2bf(v.w);
    *(ushort4*)&lw[ci*128 + co4] = h;
  }
  red[t] = sq;
  __syncthreads();
  if (t < 32) {
    f32x4 tot = red[t];
    #pragma unroll
    for (int j = 1; j < 8; ++j) {
      f32x4 o = red[t + 32*j];
      tot.x += o.x; tot.y += o.y; tot.z += o.z; tot.w += o.w;
    }
    atomicAdd(ksq + t*4 + 0, tot.x);
    atomicAdd(ksq + t*4 + 1, tot.y);
    atomicAdd(ksq + t*4 + 2, tot.z);
    atomicAdd(ksq + t*4 + 3, tot.w);
  }
  // write wt[tap][co][ci0..ci0+32)
  int co = t >> 1, h16 = (t & 1) * 16;
  union { unsigned short u[16]; uint4 q[2]; } tmp;
  #pragma unroll
  for (int i = 0; i < 16; ++i) tmp.u[i] = lw[(h16 + i)*128 + co];
  uint4* dst = (uint4*)(wt + ((size_t)tap*128 + co)*CIN + ci0 + h16);
  dst[0] = tmp.q[0]; dst[1] = tmp.q[1];
}

// ---------------- main fused kernel ----------------
// grid = 2048: bid -> b = bid>>7, u = (bid>>1)&63, py = bid&1
// block = 256 (4 waves, 2x2 over M=64(per px) x N=128)
__global__ __launch_bounds__(256) void yat_main(
    const unsigned short* __restrict__ xpad,
    const unsigned short* __restrict__ wt,
    const float* __restrict__ spad,
    const float* __restrict__ ksq,
    const float* __restrict__ bias,
    const float* __restrict__ alpha,
    float* __restrict__ out)
{
  __shared__ __align__(16) unsigned short xs[2*66*32];   // [row a][66 cols][32 ci]
  __shared__ __align__(16) unsigned short bs[128*32];    // [co][32 ci]
  __shared__ float srow[2*66];

  int bid = blockIdx.x;
  int py = bid & 1, u = (bid >> 1) & 63, b = bid >> 7;
  int t = threadIdx.x, wave = t >> 6, lane = t & 63;
  int wm = wave >> 1, wn = wave & 1;
  int l15 = lane & 15, l4 = lane >> 4;

  if (t < 132) {
    int r = t / 66, c = t - r*66;
    srow[t] = spad[((size_t)b*66 + (u + py) + r)*66 + c];
  }

  f32x4 acc[2][2][4];                                   // [px][mt][nt]
  #pragma unroll
  for (int i = 0; i < 2; ++i)
    #pragma unroll
    for (int j = 0; j < 2; ++j)
      #pragma unroll
      for (int k = 0; k < 4; ++k)
        acc[i][j][k] = (f32x4){0.f, 0.f, 0.f, 0.f};

  const size_t xrow = ((size_t)b*66 + (u + py)) * 66 * CIN;

  for (int c8 = 0; c8 < 8; ++c8) {
    int ci0 = c8 * 32;
    __syncthreads();
    // stage x: 2 rows x 66 cols x 32 ci (528 16B segments)
    #pragma unroll
    for (int i = 0; i < 2; ++i) {
      int s = i*256 + t;
      int r = (s >= 264) ? 1 : 0;
      int s2 = s - r*264;
      int c = s2 >> 2, q = s2 & 3;
      async16(&xs[(size_t)(i*256 + wave*64)*8],
              xpad + xrow + ((size_t)r*66 + c)*CIN + ci0 + q*8);
    }
    if (t < 16) {                                       // tail: segs 512..527 (r=1)
      int s2 = 248 + t;
      int c = s2 >> 2, q = s2 & 3;
      *(uint4*)&xs[(size_t)(512 + t)*8] =
          *(const uint4*)(xpad + xrow + (66 + (size_t)c)*CIN + ci0 + q*8);
    }
    for (int tap = 0; tap < 8; ++tap) {
      int a = tap >> 2, kx = tap & 3;
      int ky = py + 2*a;
      if (tap) __syncthreads();
      // stage B: w_t[ky*4+kx][0:128][ci0:ci0+32] (512 16B segments)
      #pragma unroll
      for (int i = 0; i < 2; ++i) {
        int s = i*256 + t;
        int co = s >> 2, q = s & 3;
        async16(&bs[(size_t)(i*256 + wave*64)*8],
                wt + ((size_t)(ky*4 + kx)*128 + co)*CIN + ci0 + q*8);
      }
      __syncthreads();
      int px = kx & 1, bb = kx >> 1;
      bf16x8 af[2], bfr[4];
      #pragma unroll
      for (int mt = 0; mt < 2; ++mt) {
        int c = wm*32 + mt*16 + l15 + px + bb;          // padded col = v + px + bb
        af[mt] = *(const bf16x8*)&xs[(a*66 + c)*32 + l4*8];
      }
      #pragma unroll
      for (int nt = 0; nt < 4; ++nt) {
        int n = wn*64 + nt*16 + l15;
        bfr[nt] = *(const bf16x8*)&bs[n*32 + l4*8];
      }
      #pragma unroll
      for (int mt = 0; mt < 2; ++mt)
        #pragma unroll
        for (int nt = 0; nt < 4; ++nt)
          acc[px][mt][nt] = __builtin_amdgcn_mfma_f32_16x16x32_bf16(
              af[mt], bfr[nt], acc[px][mt][nt], 0, 0, 0);
    }
  }

  // ---------------- epilogue ----------------
  float scale = powf(sqrtf(128.f) / log1pf(128.f), alpha[0]);
  int oy = 2*u + py;
  float kq[4], bi[4];
  #pragma unroll
  for (int nt = 0; nt < 4; ++nt) {
    int n = wn*64 + nt*16 + l15;
    kq[nt] = ksq[n]; bi[nt] = bias[n];
  }
  size_t orow = ((size_t)b*128 + oy) * 128 * COUT;
  #pragma unroll
  for (int px = 0; px < 2; ++px)
    #pragma unroll
    for (int mt = 0; mt < 2; ++mt) {
      int vb = wm*32 + mt*16 + l4*4;
      #pragma unroll
      for (int r = 0; r < 4; ++r) {
        int v = vb + r;
        float ps = srow[v+px] + srow[v+px+1] + srow[66 + v+px] + srow[66 + v+px+1];
        #pragma unroll
        for (int nt = 0; nt < 4; ++nt) {
          float dot = acc[px][mt][nt][r];
          float dist = ps + kq[nt] - 2.f*dot + 1e-5f;
          float y = (dot*dot/dist + bi[nt]) * scale;
          int n = wn*64 + nt*16 + l15;
          out[orow + (size_t)(2*v + px)*COUT + n] = y;
        }
      }
    }
}

// ---------------- fallback (tiny ws): direct fp32 ----------------
__global__ __launch_bounds__(256) void fb_ksq(const float* __restrict__ w,
                                              float* __restrict__ ksq) {
  __shared__ float red[256];
  int co = blockIdx.x, t = threadIdx.x;
  float s = 0.f;
  for (int j = t; j < 4096; j += 256) { float v = w[(size_t)j*COUT + co]; s += v*v; }
  red[t] = s; __syncthreads();
  for (int off = 128; off > 0; off >>= 1) {
    if (t < off) red[t] += red[t + off];
    __syncthreads();
  }
  if (t == 0) ksq[co] = red[0];
}

__global__ __launch_bounds__(256) void fb_main(
    const float* __restrict__ x, const float* __restrict__ w,
    const float* __restrict__ bias, const float* __restrict__ alpha,
    const float* __restrict__ ksq, float* __restrict__ out)
{
  size_t idx = (size_t)blockIdx.x * 256 + threadIdx.x;
  int co = (int)(idx & 127);
  int ox = (int)((idx >> 7) & 127);
  int oy = (int)((idx >> 14) & 127);
  int b  = (int)(idx >> 21);
  int py = oy & 1, px = ox & 1, u = oy >> 1, v = ox >> 1;
  float dot = 0.f, ps = 0.f;
  for (int a = 0; a < 2; ++a) {
    int iy = u + py + a - 1;
    if (iy < 0 || iy > 63) continue;
    for (int b2 = 0; b2 < 2; ++b2) {
      int ix = v + px + b2 - 1;
      if (ix < 0 || ix > 63) continue;
      const float* xp = x + (((size_t)b*64 + iy)*64 + ix)*CIN;
      const float* wp = w + ((size_t)((py + 2*a)*4 + (px + 2*b2))*CIN)*COUT + co;
      for (int ci = 0; ci < CIN; ++ci) {
        float xv = xp[ci];
        dot += xv * wp[(size_t)ci*COUT];
        ps  += xv * xv;
      }
    }
  }
  float dist = ps + ksq[co] - 2.f*dot + 1e-5f;
  float scale = powf(sqrtf(128.f) / log1pf(128.f), alpha[0]);
  out[idx] = (dot*dot/dist + bias[co]) * scale;
}

// ---------------- launcher ----------------
extern "C" void kernel_launch(void* const* d_in, const int* in_sizes, int n_in,
                              void* d_out, int out_size, void* d_ws, size_t ws_size,
                              hipStream_t stream)
{
  const float* x     = (const float*)d_in[0];
  const float* w     = (const float*)d_in[1];
  const float* bias  = (const float*)d_in[2];
  const float* alpha = (const float*)d_in[3];
  float* out = (float*)d_out;

  if (ws_size < WS_NEEDED) {
    // emergency path: only needs 512 B of scratch
    float* ksq = (float*)d_ws;
    fb_ksq<<<128, 256, 0, stream>>>(w, ksq);
    fb_main<<<131072, 256, 0, stream>>>(x, w, bias, alpha, ksq, out);
    return;
  }

  unsigned short* xpad = (unsigned short*)d_ws;
  unsigned short* wtp  = (unsigned short*)((char*)d_ws + WT_OFF);
  float* spad = (float*)((char*)d_ws + SPAD_OFF);
  float* ksq  = (float*)((char*)d_ws + KSQ_OFF);

  hipMemsetAsync(ksq, 0, 512, stream);
  prep_x<<<17424, 256, 0, stream>>>(x, xpad, spad);
  prep_w<<<128, 256, 0, stream>>>(w, wtp, ksq);
  yat_main<<<2048, 256, 0, stream>>>(xpad, wtp, spad, ksq, bias, alpha, out);
}